// Round 17
// baseline (263.656 us; speedup 1.0000x reference)
//
#include <hip/hip_runtime.h>
#include <cstdint>
#include <cstddef>

#define TT 8

#define E2_ELEMS (128*64*81)      // 663,552
#define E3_ELEMS (128*64*49)      // 401,408

typedef __attribute__((ext_vector_type(8))) short short8;
typedef __attribute__((ext_vector_type(4))) float f32x4;

// ---------------- merged small weight preps: wT1 + w2frag + w3frag ----------------
__global__ void prep_all(const float* __restrict__ w1, const float* __restrict__ w2,
                         const float* __restrict__ w3, float* __restrict__ wT1,
                         __bf16* __restrict__ w2f, __bf16* __restrict__ w3f) {
  int i = blockIdx.x * 256 + threadIdx.x;
  if (i < 8192) {                                   // conv1: [ochalf][pos][16oc]
    int oc = i >> 8, pos = i & 255;
    wT1[(oc >> 4) * 4096 + pos * 16 + (oc & 15)] = w1[oc * 256 + pos];
  } else if (i < 106496) {                          // conv2 frag, exact 3-term split
    int v = i - 8192;
    int j    = v & 7;
    int oc   = (v >> 3) & 63;
    int quad = (v >> 9) & 3;
    int ksg  = (v >> 11) & 15;
    int term = v >> 15;
    int k = ksg * 32 + quad * 8 + j;
    int ci = k >> 4, kpos = k & 15;
    float w = w2[oc * 512 + ci * 16 + kpos];
    float hf = (float)(__bf16)w;
    float r1 = w - hf;
    float mf = (float)(__bf16)r1;
    float r2 = r1 - mf;
    w2f[v] = (term == 0) ? (__bf16)w : (term == 1) ? (__bf16)r1 : (__bf16)r2;
  } else if (i < 217088) {                          // conv3 frag, pos-major K=576
    int v = i - 106496;
    int j    = v & 7;
    int oc   = (v >> 3) & 63;
    int quad = (v >> 9) & 3;
    int tk   = v >> 11;
    int term = tk / 18, kstep = tk % 18;
    int k = kstep * 32 + quad * 8 + j;
    int pos = k >> 6, ci = k & 63;
    float w = w3[oc * 576 + ci * 9 + pos];
    float hf = (float)(__bf16)w;
    float r1 = w - hf;
    float mf = (float)(__bf16)r1;
    float r2 = r1 - mf;
    w3f[v] = (term == 0) ? (__bf16)w : (term == 1) ? (__bf16)r1 : (__bf16)r2;
  }
}

// ---------------- fc1 MFMA weight prep (coalesced tiled): K'=pos*64+ci ----------------
__global__ __launch_bounds__(256) void prep_wff(const float* __restrict__ w,
                                                __bf16* __restrict__ wf) {
  __shared__ float tile[12544];                     // 32 oc x 392 (8ci x 49pos)
  int oc0 = blockIdx.x * 32;
  int ci0 = blockIdx.y * 8;
  int tid = threadIdx.x;
  for (int f = tid; f < 12544; f += 256) {
    int oc_l = f / 392, r = f - oc_l * 392;
    tile[f] = w[(size_t)(oc0 + oc_l) * 3136 + ci0 * 49 + r];
  }
  __syncthreads();
  int squad = (ci0 & 31) >> 3;
  int sadd  = ci0 >> 5;
  for (int g = tid; g < 1568; g += 256) {
    int pos = g >> 5, oc_l = g & 31;
    union { __bf16 h[8]; uint4 u; } T0, T1, T2;
    #pragma unroll
    for (int j = 0; j < 8; j++) {
      float wv = tile[oc_l * 392 + j * 49 + pos];
      float hf = (float)(__bf16)wv;
      float r1 = wv - hf;
      float mf = (float)(__bf16)r1;
      float r2 = r1 - mf;
      T0.h[j] = (__bf16)wv; T1.h[j] = (__bf16)r1; T2.h[j] = (__bf16)r2;
    }
    int s = pos * 2 + sadd;
    size_t b0 = (((size_t)s * 4 + squad) * 512 + oc0 + oc_l) * 8;
    *(uint4*)(wf + b0)           = T0.u;
    *(uint4*)(wf + b0 + 1605632) = T1.u;
    *(uint4*)(wf + b0 + 3211264) = T2.u;
  }
}

// ---------------- conv1 + fused BN partial stats ----------------
__global__ __launch_bounds__(128) void k_conv1(const float* __restrict__ x,
                                               const float* __restrict__ wT,
                                               const float* __restrict__ bias,
                                               float* __restrict__ out,
                                               float* __restrict__ pout) {
  __shared__ float xt[8064];
  int tid = threadIdx.x;
  int img = blockIdx.x >> 2;
  int q   = blockIdx.x & 3;
  int och = blockIdx.y;
  float4* dst = (float4*)xt;
  #pragma unroll
  for (int ci = 0; ci < 4; ci++) {
    const float4* s4 = (const float4*)(x + (size_t)img * 28224 + ci * 7056 + q * 1680);
    for (int i = tid; i < 504; i += 128) dst[ci * 504 + i] = s4[i];
  }
  __syncthreads();
  bool active = tid < 100;
  int oyl = tid / 20, ox = tid % 20;
  float acc[16];
  #pragma unroll
  for (int j = 0; j < 16; j++) acc[j] = 0.f;
  if (active) {
    int xb0 = oyl * 336 + ox * 4;
    const float* wh = wT + och * 4096;
    #pragma unroll 1
    for (int ci = 0; ci < 4; ci++) {
      #pragma unroll 1
      for (int ky = 0; ky < 8; ky++) {
        const float* xr = xt + ci * 2016 + xb0 + ky * 84;
        float4 xa  = *(const float4*)xr;
        float4 xbv = *(const float4*)(xr + 4);
        const float* wr = wh + (ci * 8 + ky) * 128;
        float xs[8] = {xa.x, xa.y, xa.z, xa.w, xbv.x, xbv.y, xbv.z, xbv.w};
        #pragma unroll
        for (int kx = 0; kx < 8; kx++) {
          #pragma unroll
          for (int j = 0; j < 16; j++)
            acc[j] = fmaf(xs[kx], wr[kx * 16 + j], acc[j]);
        }
      }
    }
  }
  __syncthreads();
  size_t obase = (size_t)img * 12800 + och * 6400 + (q * 5 + oyl) * 20 + ox;
  #pragma unroll
  for (int j = 0; j < 16; j++) {
    float v = 0.f;
    if (active) {
      v = acc[j] + bias[och * 16 + j];
      out[obase + j * 400] = v;
    }
    xt[j * 128 + tid] = v;
    xt[2048 + j * 128 + tid] = v * v;
  }
  __syncthreads();
  for (int off = 64; off > 0; off >>= 1) {
    if (tid < off) {
      #pragma unroll
      for (int j = 0; j < 16; j++) {
        xt[j * 128 + tid] += xt[j * 128 + tid + off];
        xt[2048 + j * 128 + tid] += xt[2048 + j * 128 + tid + off];
      }
    }
    __syncthreads();
  }
  if (tid < 16) {
    pout[(och * 16 + tid) * 512 + blockIdx.x] = xt[tid * 128];
    pout[16384 + (och * 16 + tid) * 512 + blockIdx.x] = xt[2048 + tid * 128];
  }
}

// ---------------- BN final: reduce 512 partials per channel ----------------
__global__ void k_bnfinal2(const float* __restrict__ pin, int sqoff, float n,
                           float* __restrict__ meanArr, float* __restrict__ rstdArr) {
  __shared__ float l0[256], l1[256];
  int c = blockIdx.x, tid = threadIdx.x;
  l0[tid] = pin[c * 512 + tid] + pin[c * 512 + tid + 256];
  l1[tid] = pin[sqoff + c * 512 + tid] + pin[sqoff + c * 512 + tid + 256];
  __syncthreads();
  for (int k = 128; k > 0; k >>= 1) {
    if (tid < k) { l0[tid] += l0[tid + k]; l1[tid] += l1[tid + k]; }
    __syncthreads();
  }
  if (tid == 0) {
    float m = l0[0] / n;
    float var = l1[0] / n - m * m;
    meanArr[c] = m;
    rstdArr[c] = rsqrtf(var + 1e-5f);
  }
}

// ---------------- BN + LIF stage 1 -> bit-packed spikes ----------------
__global__ void k_lif1b(const float* __restrict__ h, const float* __restrict__ mean,
                        const float* __restrict__ rstd, const float* __restrict__ g,
                        const float* __restrict__ bb, uint32_t* __restrict__ sout) {
  int idx = blockIdx.x * 256 + threadIdx.x;
  int ic = idx / 20;
  int ci = ic & 31;
  const float* hp = h + (size_t)idx * 20;
  float gm = g[ci], mm = mean[ci], rs = rstd[ci], bc = bb[ci];
  float xv[20];
  #pragma unroll
  for (int j4 = 0; j4 < 5; j4++) {
    float4 hv = ((const float4*)hp)[j4];
    xv[j4 * 4 + 0] = gm * (hv.x - mm) * rs + bc;
    xv[j4 * 4 + 1] = gm * (hv.y - mm) * rs + bc;
    xv[j4 * 4 + 2] = gm * (hv.z - mm) * rs + bc;
    xv[j4 * 4 + 3] = gm * (hv.w - mm) * rs + bc;
  }
  float v[20];
  #pragma unroll
  for (int j = 0; j < 20; j++) v[j] = 0.f;
  #pragma unroll
  for (int t = 0; t < TT; t++) {
    uint32_t w = 0;
    #pragma unroll
    for (int j = 0; j < 20; j++) {
      v[j] = v[j] + (xv[j] - v[j]) * 0.5f;
      uint32_t s = (v[j] >= 1.0f);
      w |= s << j;
      if (s) v[j] = 0.f;
    }
    sout[t * 81920 + idx] = w;
  }
}

// ---------------- conv2 via MFMA, B direct from global (no staging barriers) ----
// block = 2 imgs, 4 waves = (img_local, oc-half). wave: mt=6, nt=2. LDS ~9.2 KB.
__global__ __launch_bounds__(256) void k_conv2m(const uint32_t* __restrict__ s1b,
                                                const __bf16* __restrict__ wf,
                                                const float* __restrict__ bias,
                                                float* __restrict__ out,
                                                float* __restrict__ pout) {
  __shared__ uint32_t sp[1280];
  __shared__ float sred[1024];
  int tid = threadIdx.x;
  int img0 = blockIdx.x * 2;
  {
    const uint32_t* src = s1b + (size_t)img0 * 640;
    for (int i = tid; i < 1280; i += 256) sp[i] = src[i];
  }
  __syncthreads();
  int wave = tid >> 6, lane = tid & 63;
  int img_local = wave >> 1;
  int nh = wave & 1;
  int l15 = lane & 15, quad = lane >> 4;
  int ci_off = quad >> 1;
  int kyp = (quad & 1) * 2;
  int spb[6], sh[6];
  #pragma unroll
  for (int mt = 0; mt < 6; mt++) {
    int px = mt * 16 + l15;
    if (px > 80) px = 80;
    int oy = px / 9, ox = px - oy * 9;
    sh[mt]  = ox * 2;
    spb[mt] = img_local * 640 + ci_off * 20 + oy * 2 + kyp;
  }
  f32x4 acc[6][2];
  #pragma unroll
  for (int mt = 0; mt < 6; mt++)
    #pragma unroll
    for (int nt = 0; nt < 2; nt++) acc[mt][nt] = (f32x4){0.f, 0.f, 0.f, 0.f};

  #pragma unroll 2
  for (int ksg = 0; ksg < 16; ksg++) {
    short8 a[6];
    #pragma unroll
    for (int mt = 0; mt < 6; mt++) {
      uint32_t w0 = sp[spb[mt] + ksg * 40];
      uint32_t w1 = sp[spb[mt] + ksg * 40 + 1];
      uint32_t n0 = (w0 >> sh[mt]) & 15u;
      uint32_t n1 = (w1 >> sh[mt]) & 15u;
      union { uint32_t u[4]; short8 v; } A;
      A.u[0] = ((n0 & 1u) ? 0x3F80u : 0u) | ((n0 & 2u) ? 0x3F800000u : 0u);
      A.u[1] = ((n0 & 4u) ? 0x3F80u : 0u) | ((n0 & 8u) ? 0x3F800000u : 0u);
      A.u[2] = ((n1 & 1u) ? 0x3F80u : 0u) | ((n1 & 2u) ? 0x3F800000u : 0u);
      A.u[3] = ((n1 & 4u) ? 0x3F80u : 0u) | ((n1 & 8u) ? 0x3F800000u : 0u);
      a[mt] = A.v;
    }
    #pragma unroll
    for (int term = 0; term < 3; term++) {
      const __bf16* wb = wf + (((term * 16 + ksg)) << 11) + (quad << 9);
      #pragma unroll
      for (int nt = 0; nt < 2; nt++) {
        short8 b = *(const short8*)(wb + ((((nh << 1) | nt) << 4) + l15) * 8);
        #pragma unroll
        for (int mt = 0; mt < 6; mt++)
          acc[mt][nt] = __builtin_amdgcn_mfma_f32_16x16x32_bf16(a[mt], b, acc[mt][nt], 0, 0, 0);
      }
    }
  }
  float sl[2], sl2[2];
  #pragma unroll
  for (int nt = 0; nt < 2; nt++) {
    sl[nt] = 0.f; sl2[nt] = 0.f;
    int oc = nh * 32 + nt * 16 + l15;
    float bv = bias[oc];
    float* op = out + ((size_t)(img0 + img_local) * 64 + oc) * 81;
    #pragma unroll
    for (int mt = 0; mt < 6; mt++) {
      int pxr = mt * 16 + quad * 4;
      #pragma unroll
      for (int r = 0; r < 4; r++) {
        int px = pxr + r;
        if (px < 81) {
          float v = acc[mt][nt][r] + bv;
          op[px] = v;
          sl[nt] += v; sl2[nt] += v * v;
        }
      }
    }
  }
  #pragma unroll
  for (int nt = 0; nt < 2; nt++) {
    int oc = nh * 32 + nt * 16 + l15;
    int idx = oc * 8 + img_local * 4 + quad;
    sred[idx] = sl[nt];
    sred[512 + idx] = sl2[nt];
  }
  __syncthreads();
  if (tid < 64) {
    float s = 0.f, s2 = 0.f;
    #pragma unroll
    for (int k = 0; k < 8; k++) { s += sred[tid * 8 + k]; s2 += sred[512 + tid * 8 + k]; }
    pout[tid * 512 + blockIdx.x] = s;
    pout[32768 + tid * 512 + blockIdx.x] = s2;
  }
}

// ---------------- fused stage-2 BN+LIF + transpose -> s2T ----------------
__global__ __launch_bounds__(256) void k_lifb2T(const float* __restrict__ h,
                                                const float* __restrict__ mean,
                                                const float* __restrict__ rstd,
                                                const float* __restrict__ g,
                                                const float* __restrict__ bb,
                                                uint32_t* __restrict__ s2T) {
  __shared__ uint32_t sb[288];
  int b = blockIdx.x, half = blockIdx.y;
  int tid = threadIdx.x;
  int c1 = half * 32 + tid / 9, py1 = tid % 9;
  bool has2 = tid < 32;
  int r2 = tid + 256;
  int c2i = half * 32 + r2 / 9, py2 = r2 % 9;
  float gm1 = g[c1], mm1 = mean[c1], rs1 = rstd[c1], bc1 = bb[c1];
  float gm2 = 0.f, mm2 = 0.f, rs2 = 0.f, bc2 = 0.f;
  if (has2) { gm2 = g[c2i]; mm2 = mean[c2i]; rs2 = rstd[c2i]; bc2 = bb[c2i]; }
  float v1[9], v2[9];
  #pragma unroll
  for (int j = 0; j < 9; j++) { v1[j] = 0.f; v2[j] = 0.f; }
  size_t base1 = ((size_t)b * 64 + c1) * 81 + py1 * 9;
  size_t base2 = has2 ? ((size_t)b * 64 + c2i) * 81 + py2 * 9 : base1;
  #pragma unroll 1
  for (int t = 0; t < TT; t++) {
    const float* hp = h + (size_t)t * E2_ELEMS;
    uint32_t w = 0;
    #pragma unroll
    for (int j = 0; j < 9; j++) {
      float xv = gm1 * (hp[base1 + j] - mm1) * rs1 + bc1;
      v1[j] = v1[j] + (xv - v1[j]) * 0.5f;
      uint32_t s = (v1[j] >= 1.0f);
      w |= s << j;
      if (s) v1[j] = 0.f;
    }
    sb[tid] = w;
    if (has2) {
      uint32_t w2 = 0;
      #pragma unroll
      for (int j = 0; j < 9; j++) {
        float xv = gm2 * (hp[base2 + j] - mm2) * rs2 + bc2;
        v2[j] = v2[j] + (xv - v2[j]) * 0.5f;
        uint32_t s = (v2[j] >= 1.0f);
        w2 |= s << j;
        if (s) v2[j] = 0.f;
      }
      sb[r2] = w2;
    }
    __syncthreads();
    if (tid < 81) {
      int r = tid / 9, cpix = tid - r * 9;
      uint32_t wo = 0;
      #pragma unroll
      for (int ci = 0; ci < 32; ci++)
        wo |= ((sb[ci * 9 + r] >> cpix) & 1u) << ci;
      s2T[(size_t)(t * 128 + b) * 162 + tid * 2 + half] = wo;
    }
    __syncthreads();
  }
}

// ---------------- conv3 via MFMA, B direct from global ----------------
// block = 2 imgs, 4 waves = (img_local, oc-half). wave: mt=4, nt=2. LDS ~5.4 KB.
__global__ __launch_bounds__(256) void k_conv3m(const uint32_t* __restrict__ s2T,
                                                const __bf16* __restrict__ wf,
                                                const float* __restrict__ bias,
                                                float* __restrict__ out,
                                                float* __restrict__ pout) {
  __shared__ uint32_t sp[324];
  __shared__ float sred[1024];
  int tid = threadIdx.x;
  int img0 = blockIdx.x * 2;
  {
    const uint32_t* src = s2T + (size_t)img0 * 162;
    for (int i = tid; i < 324; i += 256) sp[i] = src[i];
  }
  __syncthreads();
  int wave = tid >> 6, lane = tid & 63;
  int img_local = wave >> 1, nh = wave & 1;
  int l15 = lane & 15, quad = lane >> 4;
  int qsh = quad * 8;
  int base[4];
  #pragma unroll
  for (int mt = 0; mt < 4; mt++) {
    int px = mt * 16 + l15;
    if (px > 48) px = 48;
    int oy = px / 7, ox = px - oy * 7;
    base[mt] = img_local * 162 + (oy * 9 + ox) * 2;
  }
  f32x4 acc[4][2];
  #pragma unroll
  for (int mt = 0; mt < 4; mt++)
    #pragma unroll
    for (int nt = 0; nt < 2; nt++) acc[mt][nt] = (f32x4){0.f, 0.f, 0.f, 0.f};

  #pragma unroll 2
  for (int kstep = 0; kstep < 18; kstep++) {
    int pos = kstep >> 1, cihalf = kstep & 1;
    int ky = pos / 3, kx = pos % 3;
    short8 a[4];
    #pragma unroll
    for (int mt = 0; mt < 4; mt++) {
      uint32_t word = sp[base[mt] + (ky * 9 + kx) * 2 + cihalf];
      uint32_t byt = (word >> qsh) & 255u;
      union { uint32_t u[4]; short8 v; } A;
      A.u[0] = ((byt & 1u)  ? 0x3F80u : 0u) | ((byt & 2u)   ? 0x3F800000u : 0u);
      A.u[1] = ((byt & 4u)  ? 0x3F80u : 0u) | ((byt & 8u)   ? 0x3F800000u : 0u);
      A.u[2] = ((byt & 16u) ? 0x3F80u : 0u) | ((byt & 32u)  ? 0x3F800000u : 0u);
      A.u[3] = ((byt & 64u) ? 0x3F80u : 0u) | ((byt & 128u) ? 0x3F800000u : 0u);
      a[mt] = A.v;
    }
    #pragma unroll
    for (int term = 0; term < 3; term++) {
      const __bf16* wb = wf + (((term * 18 + kstep)) << 11) + (quad << 9);
      #pragma unroll
      for (int nt = 0; nt < 2; nt++) {
        short8 b = *(const short8*)(wb + ((((nh << 1) | nt) << 4) + l15) * 8);
        #pragma unroll
        for (int mt = 0; mt < 4; mt++)
          acc[mt][nt] = __builtin_amdgcn_mfma_f32_16x16x32_bf16(a[mt], b, acc[mt][nt], 0, 0, 0);
      }
    }
  }
  float sl[2], sl2[2];
  #pragma unroll
  for (int nt = 0; nt < 2; nt++) {
    sl[nt] = 0.f; sl2[nt] = 0.f;
    int oc = nh * 32 + nt * 16 + l15;
    float bv = bias[oc];
    float* op = out + ((size_t)(img0 + img_local) * 64 + oc) * 49;
    #pragma unroll
    for (int mt = 0; mt < 4; mt++) {
      int pxr = mt * 16 + quad * 4;
      #pragma unroll
      for (int r = 0; r < 4; r++) {
        int px = pxr + r;
        if (px < 49) {
          float v = acc[mt][nt][r] + bv;
          op[px] = v;
          sl[nt] += v; sl2[nt] += v * v;
        }
      }
    }
  }
  #pragma unroll
  for (int nt = 0; nt < 2; nt++) {
    int oc = nh * 32 + nt * 16 + l15;
    int idx = oc * 8 + img_local * 4 + quad;
    sred[idx] = sl[nt];
    sred[512 + idx] = sl2[nt];
  }
  __syncthreads();
  if (tid < 64) {
    float s = 0.f, s2 = 0.f;
    #pragma unroll
    for (int k = 0; k < 8; k++) { s += sred[tid * 8 + k]; s2 += sred[512 + tid * 8 + k]; }
    pout[tid * 512 + blockIdx.x] = s;
    pout[32768 + tid * 512 + blockIdx.x] = s2;
  }
}

// ---------------- fused stage-3 BN+LIF + transpose -> s3T ----------------
__global__ __launch_bounds__(256) void k_lifb3T(const float* __restrict__ h,
                                                const float* __restrict__ mean,
                                                const float* __restrict__ rstd,
                                                const float* __restrict__ g,
                                                const float* __restrict__ bb,
                                                uint32_t* __restrict__ s3T) {
  __shared__ uint32_t sb[224];
  int b = blockIdx.x, half = blockIdx.y;
  int tid = threadIdx.x;
  bool active = tid < 224;
  int row = active ? tid : 0;
  int c = half * 32 + row / 7, py = row % 7;
  float gm = g[c], mm = mean[c], rs = rstd[c], bc = bb[c];
  float v[7];
  #pragma unroll
  for (int j = 0; j < 7; j++) v[j] = 0.f;
  size_t base = ((size_t)b * 64 + c) * 49 + py * 7;
  #pragma unroll 1
  for (int t = 0; t < TT; t++) {
    const float* hp = h + (size_t)t * E3_ELEMS;
    if (active) {
      uint32_t w = 0;
      #pragma unroll
      for (int j = 0; j < 7; j++) {
        float xv = gm * (hp[base + j] - mm) * rs + bc;
        v[j] = v[j] + (xv - v[j]) * 0.5f;
        uint32_t s = (v[j] >= 1.0f);
        w |= s << j;
        if (s) v[j] = 0.f;
      }
      sb[tid] = w;
    }
    __syncthreads();
    if (tid < 49) {
      int py2 = tid / 7, px = tid - py2 * 7;
      uint32_t wo = 0;
      #pragma unroll
      for (int ci = 0; ci < 32; ci++)
        wo |= ((sb[ci * 7 + py2] >> px) & 1u) << ci;
      s3T[(size_t)(t * 128 + b) * 98 + tid * 2 + half] = wo;
    }
    __syncthreads();
  }
}

// ---------------- fc1 via MFMA ----------------
__global__ __launch_bounds__(256) void k_fc1m(const uint32_t* __restrict__ s3T,
                                              const __bf16* __restrict__ wf,
                                              float* __restrict__ part) {
  __shared__ uint32_t aS[6272];                     // 64 rows x 98 ksteps
  int tid = threadIdx.x;
  int row0 = blockIdx.x * 64;
  int oc0  = blockIdx.y * 32;
  {
    const uint32_t* src = s3T + (size_t)row0 * 98;
    for (int i = tid; i < 6272; i += 256) aS[i] = src[i];
  }
  __syncthreads();
  int wave = tid >> 6, lane = tid & 63;
  int l15 = lane & 15, quad = lane >> 4;
  int qsh = quad * 8;
  f32x4 acc[4][2];
  #pragma unroll
  for (int mt = 0; mt < 4; mt++)
    #pragma unroll
    for (int nt = 0; nt < 2; nt++) acc[mt][nt] = (f32x4){0.f, 0.f, 0.f, 0.f};
  int nIter = (wave < 2) ? 25 : 24;
  #pragma unroll 1
  for (int i = 0; i < nIter; i++) {
    int ks = i * 4 + wave;
    short8 a[4];
    #pragma unroll
    for (int mt = 0; mt < 4; mt++) {
      uint32_t word = aS[(mt * 16 + l15) * 98 + ks];
      uint32_t byt = (word >> qsh) & 255u;
      union { uint32_t u[4]; short8 v; } A;
      A.u[0] = ((byt & 1u)  ? 0x3F80u : 0u) | ((byt & 2u)   ? 0x3F800000u : 0u);
      A.u[1] = ((byt & 4u)  ? 0x3F80u : 0u) | ((byt & 8u)   ? 0x3F800000u : 0u);
      A.u[2] = ((byt & 16u) ? 0x3F80u : 0u) | ((byt & 32u)  ? 0x3F800000u : 0u);
      A.u[3] = ((byt & 64u) ? 0x3F80u : 0u) | ((byt & 128u) ? 0x3F800000u : 0u);
      a[mt] = A.v;
    }
    #pragma unroll
    for (int term = 0; term < 3; term++) {
      size_t fb = ((size_t)((term * 98 + ks) * 4 + quad) * 512 + oc0 + l15) * 8;
      #pragma unroll
      for (int nt = 0; nt < 2; nt++) {
        short8 b = *(const short8*)(wf + fb + nt * 128);
        #pragma unroll
        for (int mt = 0; mt < 4; mt++)
          acc[mt][nt] = __builtin_amdgcn_mfma_f32_16x16x32_bf16(a[mt], b, acc[mt][nt], 0, 0, 0);
      }
    }
  }
  #pragma unroll
  for (int mt = 0; mt < 4; mt++) {
    #pragma unroll
    for (int nt = 0; nt < 2; nt++) {
      int oc = oc0 + nt * 16 + l15;
      #pragma unroll
      for (int r = 0; r < 4; r++) {
        int row = row0 + mt * 16 + quad * 4 + r;
        part[(size_t)wave * 524288 + (size_t)row * 512 + oc] = acc[mt][nt][r];
      }
    }
  }
}

// ---------------- fused: 4-way reduce + bias + LIF + fco + mean over T ----------
__global__ __launch_bounds__(256) void k_fc1fco(const float* __restrict__ part,
                                                const float* __restrict__ bias,
                                                const float* __restrict__ w,
                                                const float* __restrict__ fcob,
                                                float* __restrict__ out) {
  int b = blockIdx.x, tid = threadIdx.x;
  int o0 = tid, o1 = tid + 256;
  float bv0 = bias[o0], bv1 = bias[o1];
  float v0 = 0.f, v1 = 0.f;
  float a0 = 0.f, a1 = 0.f;
  #pragma unroll
  for (int t = 0; t < TT; t++) {
    int idx0 = t * 65536 + b * 512 + o0;
    float s0 = part[idx0];
    #pragma unroll
    for (int j = 1; j < 4; j++) s0 += part[(size_t)j * 524288 + idx0];
    s0 += bv0;
    v0 = v0 + (s0 - v0) * 0.5f;
    bool sp0 = (v0 >= 1.0f);
    if (sp0) v0 = 0.f;
    int idx1 = idx0 + 256;
    float s1 = part[idx1];
    #pragma unroll
    for (int j = 1; j < 4; j++) s1 += part[(size_t)j * 524288 + idx1];
    s1 += bv1;
    v1 = v1 + (s1 - v1) * 0.5f;
    bool sp1 = (v1 >= 1.0f);
    if (sp1) v1 = 0.f;
    if (sp0) { a0 += w[o0]; a1 += w[512 + o0]; }
    if (sp1) { a0 += w[o1]; a1 += w[512 + o1]; }
  }
  __shared__ float l0[256], l1[256];
  l0[tid] = a0; l1[tid] = a1; __syncthreads();
  for (int k = 128; k > 0; k >>= 1) {
    if (tid < k) { l0[tid] += l0[tid + k]; l1[tid] += l1[tid + k]; }
    __syncthreads();
  }
  if (tid == 0) {
    out[b * 2 + 0] = l0[0] * 0.125f + fcob[0];
    out[b * 2 + 1] = l1[0] * 0.125f + fcob[1];
  }
}

extern "C" void kernel_launch(void* const* d_in, const int* in_sizes, int n_in,
                              void* d_out, int out_size, void* d_ws, size_t ws_size,
                              hipStream_t stream) {
  const float* x    = (const float*)d_in[0];
  const float* c1w  = (const float*)d_in[1];
  const float* c1b  = (const float*)d_in[2];
  const float* bn1g = (const float*)d_in[3];
  const float* bn1b = (const float*)d_in[4];
  const float* c2w  = (const float*)d_in[5];
  const float* c2b  = (const float*)d_in[6];
  const float* bn2g = (const float*)d_in[7];
  const float* bn2b = (const float*)d_in[8];
  const float* c3w  = (const float*)d_in[9];
  const float* c3b  = (const float*)d_in[10];
  const float* bn3g = (const float*)d_in[11];
  const float* bn3b = (const float*)d_in[12];
  const float* fc1w = (const float*)d_in[13];
  const float* fc1b = (const float*)d_in[14];
  const float* fcow = (const float*)d_in[15];
  const float* fcob = (const float*)d_in[16];
  float* out = (float*)d_out;

  char* ws = (char*)d_ws;
  // flat layout in the 256 MiB workspace
  float*    h1     = (float*)(ws + 0);                 //  6,553,600
  uint32_t* s1bits = (uint32_t*)(ws + 6553600);        //  2,621,440
  float*    h2     = (float*)(ws + 19660800);          // 21,233,664
  float*    h3     = (float*)(ws + 46202880);          // 12,845,056
  __bf16*   w2f    = (__bf16*)(ws + 60882944);         //    196,608
  __bf16*   w3f    = (__bf16*)(ws + 61079552);         //    221,184
  uint32_t* s2T    = (uint32_t*)(ws + 61300736);       //    663,552
  float*    wT1    = (float*)(ws + 62390272);          //     32,768
  float*    st     = (float*)(ws + 64880640);          //      1,280
  __bf16*   wff    = (__bf16*)(ws + 67108864);         //  9,633,792
  float*    f1part = (float*)(ws + 76742656);          //  8,388,608
  uint32_t* s3T    = (uint32_t*)(ws + 85131264);       //    401,408
  float*    bnpart = (float*)(ws + 85532672);          //    262,144

  prep_all   <<<848, 256, 0, stream>>>(c1w, c2w, c3w, wT1, w2f, w3f);
  prep_wff   <<<dim3(16, 8), 256, 0, stream>>>(fc1w, wff);
  k_conv1    <<<dim3(512, 2), 128, 0, stream>>>(x, wT1, c1b, h1, bnpart);
  k_bnfinal2 <<<32, 256, 0, stream>>>(bnpart, 16384, 51200.f, st, st + 32);
  k_lif1b    <<<320, 256, 0, stream>>>(h1, st, st + 32, bn1g, bn1b, s1bits);

  k_conv2m   <<<512, 256, 0, stream>>>(s1bits, w2f, c2b, h2, bnpart);
  k_bnfinal2 <<<64, 256, 0, stream>>>(bnpart, 32768, 82944.f, st + 64, st + 128);
  k_lifb2T   <<<dim3(128, 2), 256, 0, stream>>>(h2, st + 64, st + 128, bn2g, bn2b, s2T);

  k_conv3m   <<<512, 256, 0, stream>>>(s2T, w3f, c3b, h3, bnpart);
  k_bnfinal2 <<<64, 256, 0, stream>>>(bnpart, 32768, 50176.f, st + 192, st + 256);
  k_lifb3T   <<<dim3(128, 2), 256, 0, stream>>>(h3, st + 192, st + 256, bn3g, bn3b, s3T);

  k_fc1m     <<<dim3(16, 16), 256, 0, stream>>>(s3T, wff, f1part);
  k_fc1fco   <<<128, 256, 0, stream>>>(f1part, fc1b, fcow, fcob, out);
}

// Round 18
// 251.913 us; speedup vs baseline: 1.0466x; 1.0466x over previous
//
#include <hip/hip_runtime.h>
#include <cstdint>
#include <cstddef>

#define TT 8

#define E2_ELEMS (128*64*81)      // 663,552
#define E3_ELEMS (128*64*49)      // 401,408

typedef __attribute__((ext_vector_type(8))) short short8;
typedef __attribute__((ext_vector_type(4))) float f32x4;

// ---------------- merged small weight preps: wT1 + w2frag + w3frag ----------------
__global__ void prep_all(const float* __restrict__ w1, const float* __restrict__ w2,
                         const float* __restrict__ w3, float* __restrict__ wT1,
                         __bf16* __restrict__ w2f, __bf16* __restrict__ w3f) {
  int i = blockIdx.x * 256 + threadIdx.x;
  if (i < 8192) {                                   // conv1: [ochalf][pos][16oc]
    int oc = i >> 8, pos = i & 255;
    wT1[(oc >> 4) * 4096 + pos * 16 + (oc & 15)] = w1[oc * 256 + pos];
  } else if (i < 106496) {                          // conv2 frag, exact 3-term split
    int v = i - 8192;
    int j    = v & 7;
    int oc   = (v >> 3) & 63;
    int quad = (v >> 9) & 3;
    int ksg  = (v >> 11) & 15;
    int term = v >> 15;
    int k = ksg * 32 + quad * 8 + j;
    int ci = k >> 4, kpos = k & 15;
    float w = w2[oc * 512 + ci * 16 + kpos];
    float hf = (float)(__bf16)w;
    float r1 = w - hf;
    float mf = (float)(__bf16)r1;
    float r2 = r1 - mf;
    w2f[v] = (term == 0) ? (__bf16)w : (term == 1) ? (__bf16)r1 : (__bf16)r2;
  } else if (i < 217088) {                          // conv3 frag, pos-major K=576
    int v = i - 106496;
    int j    = v & 7;
    int oc   = (v >> 3) & 63;
    int quad = (v >> 9) & 3;
    int tk   = v >> 11;
    int term = tk / 18, kstep = tk % 18;
    int k = kstep * 32 + quad * 8 + j;
    int pos = k >> 6, ci = k & 63;
    float w = w3[oc * 576 + ci * 9 + pos];
    float hf = (float)(__bf16)w;
    float r1 = w - hf;
    float mf = (float)(__bf16)r1;
    float r2 = r1 - mf;
    w3f[v] = (term == 0) ? (__bf16)w : (term == 1) ? (__bf16)r1 : (__bf16)r2;
  }
}

// ---------------- fc1 MFMA weight prep (coalesced tiled): K'=pos*64+ci ----------------
__global__ __launch_bounds__(256) void prep_wff(const float* __restrict__ w,
                                                __bf16* __restrict__ wf) {
  __shared__ float tile[12544];                     // 32 oc x 392 (8ci x 49pos)
  int oc0 = blockIdx.x * 32;
  int ci0 = blockIdx.y * 8;
  int tid = threadIdx.x;
  for (int f = tid; f < 12544; f += 256) {
    int oc_l = f / 392, r = f - oc_l * 392;
    tile[f] = w[(size_t)(oc0 + oc_l) * 3136 + ci0 * 49 + r];
  }
  __syncthreads();
  int squad = (ci0 & 31) >> 3;
  int sadd  = ci0 >> 5;
  for (int g = tid; g < 1568; g += 256) {
    int pos = g >> 5, oc_l = g & 31;
    union { __bf16 h[8]; uint4 u; } T0, T1, T2;
    #pragma unroll
    for (int j = 0; j < 8; j++) {
      float wv = tile[oc_l * 392 + j * 49 + pos];
      float hf = (float)(__bf16)wv;
      float r1 = wv - hf;
      float mf = (float)(__bf16)r1;
      float r2 = r1 - mf;
      T0.h[j] = (__bf16)wv; T1.h[j] = (__bf16)r1; T2.h[j] = (__bf16)r2;
    }
    int s = pos * 2 + sadd;
    size_t b0 = (((size_t)s * 4 + squad) * 512 + oc0 + oc_l) * 8;
    *(uint4*)(wf + b0)           = T0.u;
    *(uint4*)(wf + b0 + 1605632) = T1.u;
    *(uint4*)(wf + b0 + 3211264) = T2.u;
  }
}

// ---------------- conv1 + fused BN partial stats ----------------
__global__ __launch_bounds__(128) void k_conv1(const float* __restrict__ x,
                                               const float* __restrict__ wT,
                                               const float* __restrict__ bias,
                                               float* __restrict__ out,
                                               float* __restrict__ pout) {
  __shared__ float xt[8064];
  int tid = threadIdx.x;
  int img = blockIdx.x >> 2;
  int q   = blockIdx.x & 3;
  int och = blockIdx.y;
  float4* dst = (float4*)xt;
  #pragma unroll
  for (int ci = 0; ci < 4; ci++) {
    const float4* s4 = (const float4*)(x + (size_t)img * 28224 + ci * 7056 + q * 1680);
    for (int i = tid; i < 504; i += 128) dst[ci * 504 + i] = s4[i];
  }
  __syncthreads();
  bool active = tid < 100;
  int oyl = tid / 20, ox = tid % 20;
  float acc[16];
  #pragma unroll
  for (int j = 0; j < 16; j++) acc[j] = 0.f;
  if (active) {
    int xb0 = oyl * 336 + ox * 4;
    const float* wh = wT + och * 4096;
    #pragma unroll 1
    for (int ci = 0; ci < 4; ci++) {
      #pragma unroll 1
      for (int ky = 0; ky < 8; ky++) {
        const float* xr = xt + ci * 2016 + xb0 + ky * 84;
        float4 xa  = *(const float4*)xr;
        float4 xbv = *(const float4*)(xr + 4);
        const float* wr = wh + (ci * 8 + ky) * 128;
        float xs[8] = {xa.x, xa.y, xa.z, xa.w, xbv.x, xbv.y, xbv.z, xbv.w};
        #pragma unroll
        for (int kx = 0; kx < 8; kx++) {
          #pragma unroll
          for (int j = 0; j < 16; j++)
            acc[j] = fmaf(xs[kx], wr[kx * 16 + j], acc[j]);
        }
      }
    }
  }
  __syncthreads();
  size_t obase = (size_t)img * 12800 + och * 6400 + (q * 5 + oyl) * 20 + ox;
  #pragma unroll
  for (int j = 0; j < 16; j++) {
    float v = 0.f;
    if (active) {
      v = acc[j] + bias[och * 16 + j];
      out[obase + j * 400] = v;
    }
    xt[j * 128 + tid] = v;
    xt[2048 + j * 128 + tid] = v * v;
  }
  __syncthreads();
  for (int off = 64; off > 0; off >>= 1) {
    if (tid < off) {
      #pragma unroll
      for (int j = 0; j < 16; j++) {
        xt[j * 128 + tid] += xt[j * 128 + tid + off];
        xt[2048 + j * 128 + tid] += xt[2048 + j * 128 + tid + off];
      }
    }
    __syncthreads();
  }
  if (tid < 16) {
    pout[(och * 16 + tid) * 512 + blockIdx.x] = xt[tid * 128];
    pout[16384 + (och * 16 + tid) * 512 + blockIdx.x] = xt[2048 + tid * 128];
  }
}

// ---------------- BN final: reduce 512 partials per channel ----------------
__global__ void k_bnfinal2(const float* __restrict__ pin, int sqoff, float n,
                           float* __restrict__ meanArr, float* __restrict__ rstdArr) {
  __shared__ float l0[256], l1[256];
  int c = blockIdx.x, tid = threadIdx.x;
  l0[tid] = pin[c * 512 + tid] + pin[c * 512 + tid + 256];
  l1[tid] = pin[sqoff + c * 512 + tid] + pin[sqoff + c * 512 + tid + 256];
  __syncthreads();
  for (int k = 128; k > 0; k >>= 1) {
    if (tid < k) { l0[tid] += l0[tid + k]; l1[tid] += l1[tid + k]; }
    __syncthreads();
  }
  if (tid == 0) {
    float m = l0[0] / n;
    float var = l1[0] / n - m * m;
    meanArr[c] = m;
    rstdArr[c] = rsqrtf(var + 1e-5f);
  }
}

// ---------------- BN + LIF stage 1 -> bit-packed spikes ----------------
__global__ void k_lif1b(const float* __restrict__ h, const float* __restrict__ mean,
                        const float* __restrict__ rstd, const float* __restrict__ g,
                        const float* __restrict__ bb, uint32_t* __restrict__ sout) {
  int idx = blockIdx.x * 256 + threadIdx.x;
  int ic = idx / 20;
  int ci = ic & 31;
  const float* hp = h + (size_t)idx * 20;
  float gm = g[ci], mm = mean[ci], rs = rstd[ci], bc = bb[ci];
  float xv[20];
  #pragma unroll
  for (int j4 = 0; j4 < 5; j4++) {
    float4 hv = ((const float4*)hp)[j4];
    xv[j4 * 4 + 0] = gm * (hv.x - mm) * rs + bc;
    xv[j4 * 4 + 1] = gm * (hv.y - mm) * rs + bc;
    xv[j4 * 4 + 2] = gm * (hv.z - mm) * rs + bc;
    xv[j4 * 4 + 3] = gm * (hv.w - mm) * rs + bc;
  }
  float v[20];
  #pragma unroll
  for (int j = 0; j < 20; j++) v[j] = 0.f;
  #pragma unroll
  for (int t = 0; t < TT; t++) {
    uint32_t w = 0;
    #pragma unroll
    for (int j = 0; j < 20; j++) {
      v[j] = v[j] + (xv[j] - v[j]) * 0.5f;
      uint32_t s = (v[j] >= 1.0f);
      w |= s << j;
      if (s) v[j] = 0.f;
    }
    sout[t * 81920 + idx] = w;
  }
}

// ---------------- conv2 via MFMA + fused BN partial stats ----------------
// block = 2 imgs, 4 waves = (img_local, oc-half). wave: mt=6 (96px), nt=2 (32oc).
__global__ __launch_bounds__(256) void k_conv2m(const uint32_t* __restrict__ s1b,
                                                const __bf16* __restrict__ wf,
                                                const float* __restrict__ bias,
                                                float* __restrict__ out,
                                                float* __restrict__ pout) {
  __shared__ uint32_t sp[1280];
  __shared__ uint4 wl4[3072];                       // 49,152 B (reused for stats)
  __bf16* wl = (__bf16*)wl4;
  int tid = threadIdx.x;
  int img0 = blockIdx.x * 2;
  {
    const uint32_t* src = s1b + (size_t)img0 * 640;
    for (int i = tid; i < 1280; i += 256) sp[i] = src[i];
  }
  int wave = tid >> 6, lane = tid & 63;
  int img_local = wave >> 1;
  int nh = wave & 1;
  int l15 = lane & 15, quad = lane >> 4;
  int ci_off = quad >> 1;
  int kyp = (quad & 1) * 2;
  int spb[6], sh[6];
  #pragma unroll
  for (int mt = 0; mt < 6; mt++) {
    int px = mt * 16 + l15;
    if (px > 80) px = 80;
    int oy = px / 9, ox = px - oy * 9;
    sh[mt]  = ox * 2;
    spb[mt] = img_local * 640 + ci_off * 20 + oy * 2 + kyp;
  }
  f32x4 acc[6][2];
  #pragma unroll
  for (int mt = 0; mt < 6; mt++)
    #pragma unroll
    for (int nt = 0; nt < 2; nt++) acc[mt][nt] = (f32x4){0.f, 0.f, 0.f, 0.f};

  for (int kc = 0; kc < 4; kc++) {
    __syncthreads();
    for (int o = tid * 8; o < 24576; o += 2048) {
      int tk = o >> 11;
      int term = tk >> 2, ksl = tk & 3;
      const __bf16* src = wf + (((term * 16 + kc * 4 + ksl)) << 11) + (o & 2047);
      *(uint4*)(wl + o) = *(const uint4*)src;
    }
    __syncthreads();
    #pragma unroll
    for (int ks = 0; ks < 4; ks++) {
      int ksg = kc * 4 + ks;
      short8 a[6];
      #pragma unroll
      for (int mt = 0; mt < 6; mt++) {
        uint32_t w0 = sp[spb[mt] + ksg * 40];
        uint32_t w1 = sp[spb[mt] + ksg * 40 + 1];
        uint32_t n0 = (w0 >> sh[mt]) & 15u;
        uint32_t n1 = (w1 >> sh[mt]) & 15u;
        union { uint32_t u[4]; short8 v; } A;
        A.u[0] = ((n0 & 1u) ? 0x3F80u : 0u) | ((n0 & 2u) ? 0x3F800000u : 0u);
        A.u[1] = ((n0 & 4u) ? 0x3F80u : 0u) | ((n0 & 8u) ? 0x3F800000u : 0u);
        A.u[2] = ((n1 & 1u) ? 0x3F80u : 0u) | ((n1 & 2u) ? 0x3F800000u : 0u);
        A.u[3] = ((n1 & 4u) ? 0x3F80u : 0u) | ((n1 & 8u) ? 0x3F800000u : 0u);
        a[mt] = A.v;
      }
      #pragma unroll
      for (int term = 0; term < 3; term++) {
        int fb = ((term * 4 + ks) << 11) + (quad << 9);
        #pragma unroll
        for (int nt = 0; nt < 2; nt++) {
          short8 b = *(const short8*)(wl + fb + ((((nh << 1) | nt) << 4) + l15) * 8);
          #pragma unroll
          for (int mt = 0; mt < 6; mt++)
            acc[mt][nt] = __builtin_amdgcn_mfma_f32_16x16x32_bf16(a[mt], b, acc[mt][nt], 0, 0, 0);
        }
      }
    }
  }
  float sl[2], sl2[2];
  #pragma unroll
  for (int nt = 0; nt < 2; nt++) {
    sl[nt] = 0.f; sl2[nt] = 0.f;
    int oc = nh * 32 + nt * 16 + l15;
    float bv = bias[oc];
    float* op = out + ((size_t)(img0 + img_local) * 64 + oc) * 81;
    #pragma unroll
    for (int mt = 0; mt < 6; mt++) {
      int pxr = mt * 16 + quad * 4;
      #pragma unroll
      for (int r = 0; r < 4; r++) {
        int px = pxr + r;
        if (px < 81) {
          float v = acc[mt][nt][r] + bv;
          op[px] = v;
          sl[nt] += v; sl2[nt] += v * v;
        }
      }
    }
  }
  __syncthreads();
  float* sred = (float*)wl4;                        // [64oc][8] + [64oc][8]
  #pragma unroll
  for (int nt = 0; nt < 2; nt++) {
    int oc = nh * 32 + nt * 16 + l15;
    int idx = oc * 8 + img_local * 4 + quad;
    sred[idx] = sl[nt];
    sred[512 + idx] = sl2[nt];
  }
  __syncthreads();
  if (tid < 64) {
    float s = 0.f, s2 = 0.f;
    #pragma unroll
    for (int k = 0; k < 8; k++) { s += sred[tid * 8 + k]; s2 += sred[512 + tid * 8 + k]; }
    pout[tid * 512 + blockIdx.x] = s;
    pout[32768 + tid * 512 + blockIdx.x] = s2;
  }
}

// ---------------- fused stage-2 BN+LIF + transpose -> s2T ----------------
__global__ __launch_bounds__(256) void k_lifb2T(const float* __restrict__ h,
                                                const float* __restrict__ mean,
                                                const float* __restrict__ rstd,
                                                const float* __restrict__ g,
                                                const float* __restrict__ bb,
                                                uint32_t* __restrict__ s2T) {
  __shared__ uint32_t sb[288];
  int b = blockIdx.x, half = blockIdx.y;
  int tid = threadIdx.x;
  int c1 = half * 32 + tid / 9, py1 = tid % 9;
  bool has2 = tid < 32;
  int r2 = tid + 256;
  int c2i = half * 32 + r2 / 9, py2 = r2 % 9;
  float gm1 = g[c1], mm1 = mean[c1], rs1 = rstd[c1], bc1 = bb[c1];
  float gm2 = 0.f, mm2 = 0.f, rs2 = 0.f, bc2 = 0.f;
  if (has2) { gm2 = g[c2i]; mm2 = mean[c2i]; rs2 = rstd[c2i]; bc2 = bb[c2i]; }
  float v1[9], v2[9];
  #pragma unroll
  for (int j = 0; j < 9; j++) { v1[j] = 0.f; v2[j] = 0.f; }
  size_t base1 = ((size_t)b * 64 + c1) * 81 + py1 * 9;
  size_t base2 = has2 ? ((size_t)b * 64 + c2i) * 81 + py2 * 9 : base1;
  #pragma unroll 1
  for (int t = 0; t < TT; t++) {
    const float* hp = h + (size_t)t * E2_ELEMS;
    uint32_t w = 0;
    #pragma unroll
    for (int j = 0; j < 9; j++) {
      float xv = gm1 * (hp[base1 + j] - mm1) * rs1 + bc1;
      v1[j] = v1[j] + (xv - v1[j]) * 0.5f;
      uint32_t s = (v1[j] >= 1.0f);
      w |= s << j;
      if (s) v1[j] = 0.f;
    }
    sb[tid] = w;
    if (has2) {
      uint32_t w2 = 0;
      #pragma unroll
      for (int j = 0; j < 9; j++) {
        float xv = gm2 * (hp[base2 + j] - mm2) * rs2 + bc2;
        v2[j] = v2[j] + (xv - v2[j]) * 0.5f;
        uint32_t s = (v2[j] >= 1.0f);
        w2 |= s << j;
        if (s) v2[j] = 0.f;
      }
      sb[r2] = w2;
    }
    __syncthreads();
    if (tid < 81) {
      int r = tid / 9, cpix = tid - r * 9;
      uint32_t wo = 0;
      #pragma unroll
      for (int ci = 0; ci < 32; ci++)
        wo |= ((sb[ci * 9 + r] >> cpix) & 1u) << ci;
      s2T[(size_t)(t * 128 + b) * 162 + tid * 2 + half] = wo;
    }
    __syncthreads();
  }
}

// ---------------- conv3 via MFMA + fused BN partial stats ----------------
// block = 2 imgs, 4 waves = (img_local, oc-half). wave: mt=4 (49px), nt=2.
__global__ __launch_bounds__(256) void k_conv3m(const uint32_t* __restrict__ s2T,
                                                const __bf16* __restrict__ wf,
                                                const float* __restrict__ bias,
                                                float* __restrict__ out,
                                                float* __restrict__ pout) {
  __shared__ uint32_t sp[324];
  __shared__ uint4 wl4[4608];                       // 73,728 B (reused for stats)
  __bf16* wl = (__bf16*)wl4;
  int tid = threadIdx.x;
  int img0 = blockIdx.x * 2;
  {
    const uint32_t* src = s2T + (size_t)img0 * 162;
    for (int i = tid; i < 324; i += 256) sp[i] = src[i];
  }
  int wave = tid >> 6, lane = tid & 63;
  int img_local = wave >> 1, nh = wave & 1;
  int l15 = lane & 15, quad = lane >> 4;
  int qsh = quad * 8;
  int base[4];
  #pragma unroll
  for (int mt = 0; mt < 4; mt++) {
    int px = mt * 16 + l15;
    if (px > 48) px = 48;
    int oy = px / 7, ox = px - oy * 7;
    base[mt] = img_local * 162 + (oy * 9 + ox) * 2;
  }
  f32x4 acc[4][2];
  #pragma unroll
  for (int mt = 0; mt < 4; mt++)
    #pragma unroll
    for (int nt = 0; nt < 2; nt++) acc[mt][nt] = (f32x4){0.f, 0.f, 0.f, 0.f};

  #pragma unroll
  for (int kc = 0; kc < 3; kc++) {
    __syncthreads();
    #pragma unroll
    for (int it = 0; it < 18; it++) {
      const __bf16* s = wf + (((it / 6) * 18 + kc * 6 + (it % 6)) << 11) + tid * 8;
      *(uint4*)(wl + (it << 11) + tid * 8) = *(const uint4*)s;
    }
    __syncthreads();
    #pragma unroll
    for (int ksl = 0; ksl < 6; ksl++) {
      int kstep = kc * 6 + ksl;
      int pos = kstep >> 1, cihalf = kstep & 1;
      int ky = pos / 3, kx = pos % 3;
      short8 a[4];
      #pragma unroll
      for (int mt = 0; mt < 4; mt++) {
        uint32_t word = sp[base[mt] + (ky * 9 + kx) * 2 + cihalf];
        uint32_t byt = (word >> qsh) & 255u;
        union { uint32_t u[4]; short8 v; } A;
        A.u[0] = ((byt & 1u)  ? 0x3F80u : 0u) | ((byt & 2u)   ? 0x3F800000u : 0u);
        A.u[1] = ((byt & 4u)  ? 0x3F80u : 0u) | ((byt & 8u)   ? 0x3F800000u : 0u);
        A.u[2] = ((byt & 16u) ? 0x3F80u : 0u) | ((byt & 32u)  ? 0x3F800000u : 0u);
        A.u[3] = ((byt & 64u) ? 0x3F80u : 0u) | ((byt & 128u) ? 0x3F800000u : 0u);
        a[mt] = A.v;
      }
      #pragma unroll
      for (int term = 0; term < 3; term++) {
        int fb = ((term * 6 + ksl) << 11) + (quad << 9);
        #pragma unroll
        for (int nt = 0; nt < 2; nt++) {
          short8 b = *(const short8*)(wl + fb + ((((nh << 1) | nt) << 4) + l15) * 8);
          #pragma unroll
          for (int mt = 0; mt < 4; mt++)
            acc[mt][nt] = __builtin_amdgcn_mfma_f32_16x16x32_bf16(a[mt], b, acc[mt][nt], 0, 0, 0);
        }
      }
    }
  }
  float sl[2], sl2[2];
  #pragma unroll
  for (int nt = 0; nt < 2; nt++) {
    sl[nt] = 0.f; sl2[nt] = 0.f;
    int oc = nh * 32 + nt * 16 + l15;
    float bv = bias[oc];
    float* op = out + ((size_t)(img0 + img_local) * 64 + oc) * 49;
    #pragma unroll
    for (int mt = 0; mt < 4; mt++) {
      int pxr = mt * 16 + quad * 4;
      #pragma unroll
      for (int r = 0; r < 4; r++) {
        int px = pxr + r;
        if (px < 49) {
          float v = acc[mt][nt][r] + bv;
          op[px] = v;
          sl[nt] += v; sl2[nt] += v * v;
        }
      }
    }
  }
  __syncthreads();
  float* sred = (float*)wl4;
  #pragma unroll
  for (int nt = 0; nt < 2; nt++) {
    int oc = nh * 32 + nt * 16 + l15;
    int idx = oc * 8 + img_local * 4 + quad;
    sred[idx] = sl[nt];
    sred[512 + idx] = sl2[nt];
  }
  __syncthreads();
  if (tid < 64) {
    float s = 0.f, s2 = 0.f;
    #pragma unroll
    for (int k = 0; k < 8; k++) { s += sred[tid * 8 + k]; s2 += sred[512 + tid * 8 + k]; }
    pout[tid * 512 + blockIdx.x] = s;
    pout[32768 + tid * 512 + blockIdx.x] = s2;
  }
}

// ---------------- fused stage-3 BN+LIF + transpose -> s3T ----------------
__global__ __launch_bounds__(256) void k_lifb3T(const float* __restrict__ h,
                                                const float* __restrict__ mean,
                                                const float* __restrict__ rstd,
                                                const float* __restrict__ g,
                                                const float* __restrict__ bb,
                                                uint32_t* __restrict__ s3T) {
  __shared__ uint32_t sb[224];
  int b = blockIdx.x, half = blockIdx.y;
  int tid = threadIdx.x;
  bool active = tid < 224;
  int row = active ? tid : 0;
  int c = half * 32 + row / 7, py = row % 7;
  float gm = g[c], mm = mean[c], rs = rstd[c], bc = bb[c];
  float v[7];
  #pragma unroll
  for (int j = 0; j < 7; j++) v[j] = 0.f;
  size_t base = ((size_t)b * 64 + c) * 49 + py * 7;
  #pragma unroll 1
  for (int t = 0; t < TT; t++) {
    const float* hp = h + (size_t)t * E3_ELEMS;
    if (active) {
      uint32_t w = 0;
      #pragma unroll
      for (int j = 0; j < 7; j++) {
        float xv = gm * (hp[base + j] - mm) * rs + bc;
        v[j] = v[j] + (xv - v[j]) * 0.5f;
        uint32_t s = (v[j] >= 1.0f);
        w |= s << j;
        if (s) v[j] = 0.f;
      }
      sb[tid] = w;
    }
    __syncthreads();
    if (tid < 49) {
      int py2 = tid / 7, px = tid - py2 * 7;
      uint32_t wo = 0;
      #pragma unroll
      for (int ci = 0; ci < 32; ci++)
        wo |= ((sb[ci * 7 + py2] >> px) & 1u) << ci;
      s3T[(size_t)(t * 128 + b) * 98 + tid * 2 + half] = wo;
    }
    __syncthreads();
  }
}

// ---------------- fc1 via MFMA ----------------
__global__ __launch_bounds__(256) void k_fc1m(const uint32_t* __restrict__ s3T,
                                              const __bf16* __restrict__ wf,
                                              float* __restrict__ part) {
  __shared__ uint32_t aS[6272];                     // 64 rows x 98 ksteps
  int tid = threadIdx.x;
  int row0 = blockIdx.x * 64;
  int oc0  = blockIdx.y * 32;
  {
    const uint32_t* src = s3T + (size_t)row0 * 98;
    for (int i = tid; i < 6272; i += 256) aS[i] = src[i];
  }
  __syncthreads();
  int wave = tid >> 6, lane = tid & 63;
  int l15 = lane & 15, quad = lane >> 4;
  int qsh = quad * 8;
  f32x4 acc[4][2];
  #pragma unroll
  for (int mt = 0; mt < 4; mt++)
    #pragma unroll
    for (int nt = 0; nt < 2; nt++) acc[mt][nt] = (f32x4){0.f, 0.f, 0.f, 0.f};
  int nIter = (wave < 2) ? 25 : 24;
  #pragma unroll 1
  for (int i = 0; i < nIter; i++) {
    int ks = i * 4 + wave;
    short8 a[4];
    #pragma unroll
    for (int mt = 0; mt < 4; mt++) {
      uint32_t word = aS[(mt * 16 + l15) * 98 + ks];
      uint32_t byt = (word >> qsh) & 255u;
      union { uint32_t u[4]; short8 v; } A;
      A.u[0] = ((byt & 1u)  ? 0x3F80u : 0u) | ((byt & 2u)   ? 0x3F800000u : 0u);
      A.u[1] = ((byt & 4u)  ? 0x3F80u : 0u) | ((byt & 8u)   ? 0x3F800000u : 0u);
      A.u[2] = ((byt & 16u) ? 0x3F80u : 0u) | ((byt & 32u)  ? 0x3F800000u : 0u);
      A.u[3] = ((byt & 64u) ? 0x3F80u : 0u) | ((byt & 128u) ? 0x3F800000u : 0u);
      a[mt] = A.v;
    }
    #pragma unroll
    for (int term = 0; term < 3; term++) {
      size_t fb = ((size_t)((term * 98 + ks) * 4 + quad) * 512 + oc0 + l15) * 8;
      #pragma unroll
      for (int nt = 0; nt < 2; nt++) {
        short8 b = *(const short8*)(wf + fb + nt * 128);
        #pragma unroll
        for (int mt = 0; mt < 4; mt++)
          acc[mt][nt] = __builtin_amdgcn_mfma_f32_16x16x32_bf16(a[mt], b, acc[mt][nt], 0, 0, 0);
      }
    }
  }
  #pragma unroll
  for (int mt = 0; mt < 4; mt++) {
    #pragma unroll
    for (int nt = 0; nt < 2; nt++) {
      int oc = oc0 + nt * 16 + l15;
      #pragma unroll
      for (int r = 0; r < 4; r++) {
        int row = row0 + mt * 16 + quad * 4 + r;
        part[(size_t)wave * 524288 + (size_t)row * 512 + oc] = acc[mt][nt][r];
      }
    }
  }
}

// ---------------- fused: 4-way reduce + bias + LIF + fco + mean over T ----------
__global__ __launch_bounds__(256) void k_fc1fco(const float* __restrict__ part,
                                                const float* __restrict__ bias,
                                                const float* __restrict__ w,
                                                const float* __restrict__ fcob,
                                                float* __restrict__ out) {
  int b = blockIdx.x, tid = threadIdx.x;
  int o0 = tid, o1 = tid + 256;
  float bv0 = bias[o0], bv1 = bias[o1];
  float v0 = 0.f, v1 = 0.f;
  float a0 = 0.f, a1 = 0.f;
  #pragma unroll
  for (int t = 0; t < TT; t++) {
    int idx0 = t * 65536 + b * 512 + o0;
    float s0 = part[idx0];
    #pragma unroll
    for (int j = 1; j < 4; j++) s0 += part[(size_t)j * 524288 + idx0];
    s0 += bv0;
    v0 = v0 + (s0 - v0) * 0.5f;
    bool sp0 = (v0 >= 1.0f);
    if (sp0) v0 = 0.f;
    int idx1 = idx0 + 256;
    float s1 = part[idx1];
    #pragma unroll
    for (int j = 1; j < 4; j++) s1 += part[(size_t)j * 524288 + idx1];
    s1 += bv1;
    v1 = v1 + (s1 - v1) * 0.5f;
    bool sp1 = (v1 >= 1.0f);
    if (sp1) v1 = 0.f;
    if (sp0) { a0 += w[o0]; a1 += w[512 + o0]; }
    if (sp1) { a0 += w[o1]; a1 += w[512 + o1]; }
  }
  __shared__ float l0[256], l1[256];
  l0[tid] = a0; l1[tid] = a1; __syncthreads();
  for (int k = 128; k > 0; k >>= 1) {
    if (tid < k) { l0[tid] += l0[tid + k]; l1[tid] += l1[tid + k]; }
    __syncthreads();
  }
  if (tid == 0) {
    out[b * 2 + 0] = l0[0] * 0.125f + fcob[0];
    out[b * 2 + 1] = l1[0] * 0.125f + fcob[1];
  }
}

extern "C" void kernel_launch(void* const* d_in, const int* in_sizes, int n_in,
                              void* d_out, int out_size, void* d_ws, size_t ws_size,
                              hipStream_t stream) {
  const float* x    = (const float*)d_in[0];
  const float* c1w  = (const float*)d_in[1];
  const float* c1b  = (const float*)d_in[2];
  const float* bn1g = (const float*)d_in[3];
  const float* bn1b = (const float*)d_in[4];
  const float* c2w  = (const float*)d_in[5];
  const float* c2b  = (const float*)d_in[6];
  const float* bn2g = (const float*)d_in[7];
  const float* bn2b = (const float*)d_in[8];
  const float* c3w  = (const float*)d_in[9];
  const float* c3b  = (const float*)d_in[10];
  const float* bn3g = (const float*)d_in[11];
  const float* bn3b = (const float*)d_in[12];
  const float* fc1w = (const float*)d_in[13];
  const float* fc1b = (const float*)d_in[14];
  const float* fcow = (const float*)d_in[15];
  const float* fcob = (const float*)d_in[16];
  float* out = (float*)d_out;

  char* ws = (char*)d_ws;
  // flat layout in the 256 MiB workspace (no overlays)
  float*    h1     = (float*)(ws + 0);                 //  6,553,600
  uint32_t* s1bits = (uint32_t*)(ws + 6553600);        //  2,621,440
  float*    h2     = (float*)(ws + 19660800);          // 21,233,664
  float*    h3     = (float*)(ws + 46202880);          // 12,845,056
  __bf16*   w2f    = (__bf16*)(ws + 60882944);         //    196,608
  __bf16*   w3f    = (__bf16*)(ws + 61079552);         //    221,184
  uint32_t* s2T    = (uint32_t*)(ws + 61300736);       //    663,552
  float*    wT1    = (float*)(ws + 62390272);          //     32,768
  float*    st     = (float*)(ws + 64880640);          //      1,280
  __bf16*   wff    = (__bf16*)(ws + 67108864);         //  9,633,792
  float*    f1part = (float*)(ws + 76742656);          //  8,388,608
  uint32_t* s3T    = (uint32_t*)(ws + 85131264);       //    401,408
  float*    bnpart = (float*)(ws + 85532672);          //    262,144

  prep_all   <<<848, 256, 0, stream>>>(c1w, c2w, c3w, wT1, w2f, w3f);
  prep_wff   <<<dim3(16, 8), 256, 0, stream>>>(fc1w, wff);
  k_conv1    <<<dim3(512, 2), 128, 0, stream>>>(x, wT1, c1b, h1, bnpart);
  k_bnfinal2 <<<32, 256, 0, stream>>>(bnpart, 16384, 51200.f, st, st + 32);
  k_lif1b    <<<320, 256, 0, stream>>>(h1, st, st + 32, bn1g, bn1b, s1bits);

  k_conv2m   <<<512, 256, 0, stream>>>(s1bits, w2f, c2b, h2, bnpart);
  k_bnfinal2 <<<64, 256, 0, stream>>>(bnpart, 32768, 82944.f, st + 64, st + 128);
  k_lifb2T   <<<dim3(128, 2), 256, 0, stream>>>(h2, st + 64, st + 128, bn2g, bn2b, s2T);

  k_conv3m   <<<512, 256, 0, stream>>>(s2T, w3f, c3b, h3, bnpart);
  k_bnfinal2 <<<64, 256, 0, stream>>>(bnpart, 32768, 50176.f, st + 192, st + 256);
  k_lifb3T   <<<dim3(128, 2), 256, 0, stream>>>(h3, st + 192, st + 256, bn3g, bn3b, s3T);

  k_fc1m     <<<dim3(16, 16), 256, 0, stream>>>(s3T, wff, f1part);
  k_fc1fco   <<<128, 256, 0, stream>>>(f1part, fc1b, fcow, fcob, out);
}